// Round 4
// baseline (697.407 us; speedup 1.0000x reference)
//
#include <hip/hip_runtime.h>
#include <hip/hip_bf16.h>
#include <math.h>

#define FDIM 15
#define FPAD 16
#define NEG_SLOPE 0.2f
// edge-pass kernels: 256 blocks x 1024 thr grid-stride
#define HB_GRID 256
#define HB_BLK 1024
// scan geometry: 1024 thr x 4 elems = 4096 per block (N<=262144 -> <=64 blocks)
#define SCAN_BLK 1024
#define SCAN_ELEMS 4096

typedef _Float16 half_t;

__device__ __forceinline__ float leaky(float e) {
  return fmaxf(NEG_SLOPE * e, e);   // valid for slope<1
}

__global__ void k_zero(int* __restrict__ p, int n) {
  int i = blockIdx.x * blockDim.x + threadIdx.x;
  if (i < n) p[i] = 0;
}

// ---- R20 direct CSR build, pass 1: per-dst degree count (real edges) ----
__global__ void k_dhist(const int* __restrict__ dstI, int* __restrict__ rowcnt,
                        int E, int vec_ok) {
  int tid = blockIdx.x * blockDim.x + threadIdx.x;
  int nthr = gridDim.x * blockDim.x;
  int nv = vec_ok ? (E >> 2) : 0;
  const int4* d4 = (const int4*)dstI;
  for (int i = tid; i < nv; i += nthr) {
    int4 v = d4[i];
    atomicAdd(&rowcnt[v.x], 1);
    atomicAdd(&rowcnt[v.y], 1);
    atomicAdd(&rowcnt[v.z], 1);
    atomicAdd(&rowcnt[v.w], 1);
  }
  for (int i = (nv << 2) + tid; i < E; i += nthr)
    atomicAdd(&rowcnt[dstI[i]], 1);
}

// ---- scan phase 1: per-block exclusive scan of (rowcnt[i]+1) ----
// rowptr[i] <- block-local exclusive prefix; blkSum[b] <- block total
__global__ void k_scan1(const int* __restrict__ rowcnt, int* __restrict__ rowptr,
                        int* __restrict__ blkSum, int N) {
  __shared__ int ts[SCAN_BLK];
  int t = threadIdx.x;
  int base = blockIdx.x * SCAN_ELEMS + t * 4;
  int v0 = 0, v1 = 0, v2 = 0, v3 = 0;
  if (base + 3 < N) {
    int4 c = *(const int4*)(rowcnt + base);
    v0 = c.x + 1; v1 = c.y + 1; v2 = c.z + 1; v3 = c.w + 1;
  } else {
    if (base     < N) v0 = rowcnt[base] + 1;
    if (base + 1 < N) v1 = rowcnt[base + 1] + 1;
    if (base + 2 < N) v2 = rowcnt[base + 2] + 1;
  }
  int tsum = v0 + v1 + v2 + v3;
  ts[t] = tsum;
  __syncthreads();
  for (int off = 1; off < SCAN_BLK; off <<= 1) {
    int add = (t >= off) ? ts[t - off] : 0;
    __syncthreads();
    ts[t] += add;
    __syncthreads();
  }
  int excl = ts[t] - tsum;
  int p0 = excl, p1 = excl + v0, p2 = p1 + v1, p3 = p2 + v2;
  if (base + 3 < N) {
    *(int4*)(rowptr + base) = make_int4(p0, p1, p2, p3);
  } else {
    if (base     < N) rowptr[base]     = p0;
    if (base + 1 < N) rowptr[base + 1] = p1;
    if (base + 2 < N) rowptr[base + 2] = p2;
  }
  if (t == SCAN_BLK - 1) blkSum[blockIdx.x] = ts[t];
}

// ---- scan phase 2: exclusive scan of <=64 block sums ----
__global__ void k_scan2(int* __restrict__ blkSum, int nblk) {
  __shared__ int s[64];
  int t = threadIdx.x;  // 64
  int v = (t < nblk) ? blkSum[t] : 0;
  s[t] = v;
  __syncthreads();
  for (int off = 1; off < 64; off <<= 1) {
    int add = (t >= off) ? s[t - off] : 0;
    __syncthreads();
    s[t] += add;
    __syncthreads();
  }
  if (t < nblk) blkSum[t] = s[t] - v;
}

// ---- scan phase 3: finalize rowptr, init rcur, pre-place self-loops ----
// row layout: [rowptr[d], rowptr[d]+rowcnt[d]) real edges (filled by scatter),
// slot rowptr[d]+rowcnt[d] = rowptr[d+1]-1 carries the self loop (placed here).
__global__ void k_scan3(const int* __restrict__ rowcnt, int* __restrict__ rowptr,
                        const int* __restrict__ blkSum, int* __restrict__ rcur,
                        int* __restrict__ csr, int N, int total) {
  int i = blockIdx.x * blockDim.x + threadIdx.x;
  if (i >= N) return;
  int off = blkSum[i / SCAN_ELEMS];
  int rp = rowptr[i] + off;
  rowptr[i] = rp;
  rcur[i] = rp;
  csr[rp + rowcnt[i]] = i << 5;   // self loop, pre-scaled src*32 bytes
  if (i == N - 1) rowptr[N] = total;
}

// ---- R20 direct CSR build, pass 2: scatter edges into rows ----
__global__ void k_scatter(const int* __restrict__ srcI, const int* __restrict__ dstI,
                          int* __restrict__ rcur, int* __restrict__ csr,
                          int E, int vec_ok) {
  int tid = blockIdx.x * blockDim.x + threadIdx.x;
  int nthr = gridDim.x * blockDim.x;
  int nv = vec_ok ? (E >> 2) : 0;
  const int4* s4 = (const int4*)srcI;
  const int4* d4 = (const int4*)dstI;
  for (int i = tid; i < nv; i += nthr) {
    int4 s = s4[i];
    int4 d = d4[i];
    int p0 = atomicAdd(&rcur[d.x], 1);
    int p1 = atomicAdd(&rcur[d.y], 1);
    int p2 = atomicAdd(&rcur[d.z], 1);
    int p3 = atomicAdd(&rcur[d.w], 1);
    csr[p0] = s.x << 5;
    csr[p1] = s.y << 5;
    csr[p2] = s.z << 5;
    csr[p3] = s.w << 5;
  }
  for (int i = (nv << 2) + tid; i < E; i += nthr) {
    int p = atomicAdd(&rcur[dstI[i]], 1);
    csr[p] = srcI[i] << 5;
  }
}

// ---- h = in @ W (fp16, as packed in slot 15) ; ad_ fp32 (layer 0 only) ----
__global__ void k_transform(const float* __restrict__ in, int ld_in,
                            const float* __restrict__ W,
                            const float* __restrict__ a_s,
                            const float* __restrict__ a_d,
                            half_t* __restrict__ hp,
                            float* __restrict__ ad_,
                            int n_nodes) {
  __shared__ float Ws[FDIM * FDIM];
  __shared__ float asv[FDIM], adv[FDIM];
  int tid = threadIdx.x;
  if (tid < FDIM * FDIM) Ws[tid] = W[tid];
  if (tid < FDIM) { asv[tid] = a_s[tid]; adv[tid] = a_d[tid]; }
  __syncthreads();
  int n = blockIdx.x * blockDim.x + tid;
  if (n >= n_nodes) return;
  float xin[FDIM];
#pragma unroll
  for (int j = 0; j < FDIM; ++j) xin[j] = in[n * ld_in + j];
  float sa = 0.f, da = 0.f;
  half_t hrow[FPAD];
#pragma unroll
  for (int o = 0; o < FDIM; ++o) {
    float acc = 0.f;
#pragma unroll
    for (int k = 0; k < FDIM; ++k) acc += xin[k] * Ws[k * FDIM + o];
    hrow[o] = (half_t)acc;
    sa += acc * asv[o];
    da += acc * adv[o];
  }
  hrow[FDIM] = (half_t)sa;
  ad_[n] = da;
  float4 w0, w1;
  __builtin_memcpy(&w0, &hrow[0], 16);
  __builtin_memcpy(&w1, &hrow[8], 16);
  float4* dst = (float4*)(hp + (size_t)n * FPAD);
  dst[0] = w0;
  dst[1] = w1;
}

// ---- annotation-MLP stage rider: 8-way explicit ILP (R16 lesson: rider
// block lifetime = displacement window; R11 lesson: only explicit scalar
// loads produce loads-in-flight on this compiler) ----
__device__ __forceinline__ void mlp_rider(int g, int tid, int nthreads,
                                          const float* __restrict__ mIn,
                                          const float* __restrict__ mW,
                                          const float* __restrict__ mB,
                                          float* __restrict__ mOut,
                                          int Nout, int mAct,
                                          float* mins) {
  for (int k = tid; k < 300; k += nthreads) mins[k] = mIn[(size_t)g * 300 + k];
  __syncthreads();
  int j1 = tid;
  int j2 = tid + nthreads;
  bool p1 = (j1 < Nout), p2 = (j2 < Nout);
  if (!p1) return;
  float a0 = 0.f, a1 = 0.f, a2 = 0.f, a3 = 0.f;
  float a4 = 0.f, a5 = 0.f, a6 = 0.f, a7 = 0.f;
  float b0 = 0.f, b1 = 0.f, b2 = 0.f, b3 = 0.f;
  float b4 = 0.f, b5 = 0.f, b6 = 0.f, b7 = 0.f;
  int k = 0;
  for (; k + 7 < 300; k += 8) {
    float i0 = mins[k],     i1 = mins[k + 1], i2 = mins[k + 2], i3 = mins[k + 3];
    float i4 = mins[k + 4], i5 = mins[k + 5], i6 = mins[k + 6], i7 = mins[k + 7];
    float w0 = mW[k * Nout + j1];
    float w1 = mW[(k + 1) * Nout + j1];
    float w2 = mW[(k + 2) * Nout + j1];
    float w3 = mW[(k + 3) * Nout + j1];
    float w4 = mW[(k + 4) * Nout + j1];
    float w5 = mW[(k + 5) * Nout + j1];
    float w6 = mW[(k + 6) * Nout + j1];
    float w7 = mW[(k + 7) * Nout + j1];
    a0 += i0 * w0; a1 += i1 * w1; a2 += i2 * w2; a3 += i3 * w3;
    a4 += i4 * w4; a5 += i5 * w5; a6 += i6 * w6; a7 += i7 * w7;
    if (p2) {
      float v0 = mW[k * Nout + j2];
      float v1 = mW[(k + 1) * Nout + j2];
      float v2 = mW[(k + 2) * Nout + j2];
      float v3 = mW[(k + 3) * Nout + j2];
      float v4 = mW[(k + 4) * Nout + j2];
      float v5 = mW[(k + 5) * Nout + j2];
      float v6 = mW[(k + 6) * Nout + j2];
      float v7 = mW[(k + 7) * Nout + j2];
      b0 += i0 * v0; b1 += i1 * v1; b2 += i2 * v2; b3 += i3 * v3;
      b4 += i4 * v4; b5 += i5 * v5; b6 += i6 * v6; b7 += i7 * v7;
    }
  }
  for (; k < 300; ++k) {
    float ik = mins[k];
    a0 += ik * mW[k * Nout + j1];
    if (p2) b0 += ik * mW[k * Nout + j2];
  }
  float r1 = mB[j1] + ((a0 + a1) + (a2 + a3)) + ((a4 + a5) + (a6 + a7));
  if (mAct == 1) r1 = fmaxf(r1, 0.f);
  else if (mAct == 2) r1 = 1.f / (1.f + expf(-r1));
  mOut[(size_t)g * Nout + j1] = r1;
  if (p2) {
    float r2 = mB[j2] + ((b0 + b1) + (b2 + b3)) + ((b4 + b5) + (b6 + b7));
    if (mAct == 1) r2 = fmaxf(r2, 0.f);
    else if (mAct == 2) r2 = 1.f / (1.f + expf(-r2));
    mOut[(size_t)g * Nout + j2] = r2;
  }
}

// ---- fused GAT aggregate + FFN (+ next-layer transform) + MLP rider ----
// R19: one-lane-per-edge. Lane f owns edge j+f whole: 1 coalesced csr
// load, 2x dwordx4 row gather (32B), sa local (no per-edge shfl), weight
// computed once per edge. Row epilogue: 15-shfl halving butterfly; lane f
// ends with feature brev4(f); slot 15 carries den. cb-bias and 1/den are
// folded into the FFN via cbW[o] = sum_k cb[k]*W[k][o].
__global__ void k_gat(const int* __restrict__ rowptr, const int* __restrict__ csrB,
                      const half_t* __restrict__ hp, const float* __restrict__ ad_,
                      const float* __restrict__ cb, const float* __restrict__ fW,
                      const float* __restrict__ fb,
                      const float* __restrict__ nW, const float* __restrict__ nas,
                      const float* __restrict__ nad,
                      half_t* __restrict__ hp2, float* __restrict__ ad2,
                      float* __restrict__ fout,
                      const float* __restrict__ mIn, const float* __restrict__ mW,
                      const float* __restrict__ mB, float* __restrict__ mOut,
                      int mNout, int mAct, int mlpG,
                      int n_nodes, int do_relu, int fuse) {
  __shared__ float Ws[FDIM * FDIM];
  __shared__ float W2s[FDIM * FDIM];
  __shared__ float cbv[FDIM], fbv[FDIM], as2v[FDIM], ad2v[FDIM];
  __shared__ float cbW[16];
  __shared__ float aggT[16][16];
  __shared__ float outT[16][16];
  __shared__ float mins[304];
  int tid = threadIdx.x;

  if ((int)blockIdx.x < mlpG) {
    mlp_rider(blockIdx.x, tid, blockDim.x, mIn, mW, mB, mOut, mNout, mAct, mins);
    return;
  }

  if (tid < FDIM * FDIM) Ws[tid] = fW[tid];
  if (tid < FDIM) { cbv[tid] = cb[tid]; fbv[tid] = fb[tid]; }
  if (fuse) {
    if (tid < FDIM * FDIM) W2s[tid] = nW[tid];
    if (tid < FDIM) { as2v[tid] = nas[tid]; ad2v[tid] = nad[tid]; }
  }
  __syncthreads();
  // fold cb into FFN: cbW[o] = sum_k cb[k] * W[k][o]
  if (tid < 16) {
    float s = 0.f;
    if (tid < FDIM) {
#pragma unroll
      for (int k = 0; k < FDIM; ++k) s += cbv[k] * Ws[k * FDIM + tid];
    }
    cbW[tid] = s;
  }
  int dl = tid >> 4;          // local dst 0..15
  int f  = tid & 15;          // lane-in-group = edge slot
  int d  = ((int)blockIdx.x - mlpG) * 16 + dl;
  if (d < n_nodes) {
    int rs = rowptr[d], re = rowptr[d + 1];   // re > rs always (self loop)
    int rlast = re - 1;
    float adv = ad_[d];
    const char* hb = (const char*)hp;
    float acc[16];
#pragma unroll
    for (int k = 0; k < 16; ++k) acc[k] = 0.f;

    // prologue: offsets+gathers for step 0; offsets for step 1
    int i0 = rs + f;
    int oA = csrB[i0 < re ? i0 : rlast];
    uint4 aLo = *(const uint4*)(hb + oA);
    uint4 aHi = *(const uint4*)(hb + oA + 16);
    int i1 = i0 + 16;
    int oB = csrB[i1 < re ? i1 : rlast];

    for (int j = rs; j < re; j += 16) {
      // gathers for next step
      uint4 bLo = *(const uint4*)(hb + oB);
      uint4 bHi = *(const uint4*)(hb + oB + 16);
      // offsets for step after next
      int i2 = j + 32 + f;
      int oC = csrB[i2 < re ? i2 : rlast];
      // compute current edge j+f
      half_t hv[16];
      __builtin_memcpy(hv, &aLo, 16);
      __builtin_memcpy(hv + 8, &aHi, 16);
      float sa = (float)hv[15];
      float w = (j + f < re) ? __expf(leaky(sa + adv)) : 0.f;
#pragma unroll
      for (int k = 0; k < FDIM; ++k) acc[k] += w * (float)hv[k];
      acc[15] += w;   // den rides in slot 15
      // rotate pipeline
      aLo = bLo; aHi = bHi; oB = oC;
    }

    // 16-lane halving butterfly: lane f ends with sum over lanes of
    // feature brev4(f) in acc[0] (slot 15 = den lands on lane 15).
    {
      bool hi = (f & 1);
#pragma unroll
      for (int i = 0; i < 8; ++i) {
        float send = hi ? acc[i] : acc[8 + i];
        float got = __shfl_xor(send, 1, 16);
        acc[i] = (hi ? acc[8 + i] : acc[i]) + got;
      }
      hi = (f & 2);
#pragma unroll
      for (int i = 0; i < 4; ++i) {
        float send = hi ? acc[i] : acc[4 + i];
        float got = __shfl_xor(send, 2, 16);
        acc[i] = (hi ? acc[4 + i] : acc[i]) + got;
      }
      hi = (f & 4);
#pragma unroll
      for (int i = 0; i < 2; ++i) {
        float send = hi ? acc[i] : acc[2 + i];
        float got = __shfl_xor(send, 4, 16);
        acc[i] = (hi ? acc[2 + i] : acc[i]) + got;
      }
      hi = (f & 8);
      {
        float send = hi ? acc[0] : acc[1];
        float got = __shfl_xor(send, 8, 16);
        acc[0] = (hi ? acc[1] : acc[0]) + got;
      }
    }
    int fb = ((f & 1) << 3) | ((f & 2) << 1) | ((f & 4) >> 1) | ((f & 8) >> 3);
    aggT[dl][fb] = acc[0];   // raw weighted sums; [15] = den
  }
  __syncthreads();
  int o = f;
  float ffn = 0.f;
  if (o < FDIM && d < n_nodes) {
    float inv = 1.f / (aggT[dl][15] + 1e-16f);
    float s = 0.f;
#pragma unroll
    for (int k = 0; k < FDIM; ++k) s += aggT[dl][k] * Ws[k * FDIM + o];
    ffn = fbv[o] + cbW[o] + s * inv;
    if (do_relu) ffn = fmaxf(ffn, 0.f);
  }
  if (!fuse) {
    if (d < n_nodes) fout[d * FPAD + o] = (o < FDIM) ? ffn : 0.f;
    return;
  }
  // ---- fused next-layer transform: h2 = out @ nW ; sa2/da2 reductions ----
  outT[dl][o] = ffn;   // o==15 lane wrote ffn=0; invalid-d rows unused
  __syncthreads();
  if (d < n_nodes) {
    float h2 = 0.f;
    if (o < FDIM) {
#pragma unroll
      for (int k = 0; k < FDIM; ++k) h2 += outT[dl][k] * W2s[k * FDIM + o];
    }
    float pa = (o < FDIM) ? h2 * as2v[o] : 0.f;
    float pd = (o < FDIM) ? h2 * ad2v[o] : 0.f;
#pragma unroll
    for (int k = 8; k; k >>= 1) {
      pa += __shfl_xor(pa, k, 16);
      pd += __shfl_xor(pd, k, 16);
    }
    hp2[(size_t)d * FPAD + o] = (half_t)((o < FDIM) ? h2 : pa);
    if (o == 0) ad2[d] = pd;
  }
}

// ---- pooling + s4 rider (xann = sigmoidActs @ aW4 + ab4) ----
__device__ __forceinline__ int lowerb(const int* __restrict__ a, int n, int key) {
  int lo = 0, hi = n;
  while (lo < hi) { int mid = (lo + hi) >> 1; if (a[mid] < key) lo = mid + 1; else hi = mid; }
  return lo;
}

__global__ void k_pool(const float* __restrict__ fout, const int* __restrict__ batch,
                       float* __restrict__ pooled,
                       const float* __restrict__ acts,
                       const float* __restrict__ aW4, const float* __restrict__ ab4,
                       float* __restrict__ xann,
                       int n_nodes, int Gn) {
  __shared__ float ss[256], sm[256];
  __shared__ float mins[304];
  int tid = threadIdx.x;
  if ((int)blockIdx.x < Gn) {
    mlp_rider(blockIdx.x, tid, blockDim.x, acts, aW4, ab4, xann, 45, 0, mins);
    return;
  }
  int g = blockIdx.x - Gn;
  int s = lowerb(batch, n_nodes, g);
  int e = lowerb(batch, n_nodes, g + 1);
  int f = tid & 15;
  float sum = 0.f, mx = -INFINITY;
  for (int n = s + (tid >> 4); n < e; n += 16) {
    float v = fout[n * FPAD + f];
    sum += v;
    mx = fmaxf(mx, v);
  }
  ss[tid] = sum; sm[tid] = mx;
  __syncthreads();
  for (int step = 128; step >= 16; step >>= 1) {
    if (tid < step) { ss[tid] += ss[tid + step]; sm[tid] = fmaxf(sm[tid], sm[tid + step]); }
    __syncthreads();
  }
  if (tid < FDIM) {
    float cnt = (float)(e - s);
    float sv = ss[tid];
    pooled[g * 45 + tid] = sv;
    pooled[g * 45 + 15 + tid] = sm[tid];
    pooled[g * 45 + 30 + tid] = sv / fmaxf(cnt, 1.f);
  }
}

// ---- head: z=[pooled,xann] -> relu(z@m1W+m1b) -> sigmoid(@m2W+m2b) ----
__global__ void k_final(const float* __restrict__ pooled, const float* __restrict__ xann,
                        const float* __restrict__ m1W, const float* __restrict__ m1b,
                        const float* __restrict__ m2W, const float* __restrict__ m2b,
                        float* __restrict__ out) {
  __shared__ float z[90];
  __shared__ float z2[90];
  __shared__ float ps[128];
  int g = blockIdx.x;
  int t = threadIdx.x;  // 128
  if (t < 45) z[t] = pooled[g * 45 + t];
  else if (t < 90) z[t] = xann[g * 45 + (t - 45)];
  __syncthreads();
  if (t < 90) {
    float a0 = 0.f, a1 = 0.f;
    for (int k = 0; k < 90; k += 2) {
      float w0 = m1W[k * 90 + t];
      float w1 = m1W[(k + 1) * 90 + t];
      a0 += z[k] * w0; a1 += z[k + 1] * w1;
    }
    z2[t] = fmaxf(m1b[t] + a0 + a1, 0.f);
  }
  __syncthreads();
  if (t < 90) ps[t] = z2[t] * m2W[t];
  else ps[t] = 0.f;
  __syncthreads();
  if (t < 64) {
    float v = ps[t] + ps[t + 64];
#pragma unroll
    for (int k2 = 32; k2; k2 >>= 1) v += __shfl_xor(v, k2, 64);
    if (t == 0) out[g] = 1.f / (1.f + expf(-(v + m2b[0])));
  }
}

extern "C" void kernel_launch(void* const* d_in, const int* in_sizes, int n_in,
                              void* d_out, int out_size, void* d_ws, size_t ws_size,
                              hipStream_t stream) {
  const float* x   = (const float*)d_in[0];
  const int* ei    = (const int*)d_in[1];
  const int* batch = (const int*)d_in[2];
  const float* xA  = (const float*)d_in[3];

  const int N = in_sizes[0] / FDIM;
  const int E = in_sizes[1] / 2;
  const int G = in_sizes[3] / 300;
  const int ET = E + N;

  const int* srcI = ei;
  const int* dstI = ei + E;

  // ---- workspace layout (4-byte words) ----
  float* ws = (float*)d_ws;
  size_t layerW = (size_t)34 * N;  // hpA(8N)+hpB(8N)+adA(N)+adB(N)+fout(16N)
  size_t uSize = layerW > (size_t)(2 * N) ? layerW : (size_t)(2 * N);
  uSize = (uSize + 3) & ~(size_t)3;   // keep following arrays 16B-aligned
  size_t off = 0;
  // build-phase aliases of the layer union region (dead before k_transform)
  int*    rowcnt = (int*)(ws + off);
  int*    rcur   = (int*)(ws + off) + N;
  half_t* hpA  = (half_t*)(ws + off);
  half_t* hpB  = (half_t*)(ws + off + (size_t)8 * N);
  float*  adA  = ws + off + (size_t)16 * N;
  float*  adB  = ws + off + (size_t)17 * N;
  float*  fout = ws + off + (size_t)18 * N;
  off += uSize;
  int*   rowptr = (int*)(ws + off); off += N + 1;
  int*   csr    = (int*)(ws + off); off += (size_t)ET;
  int*   blkSum = (int*)(ws + off); off += 64;
  float* pooled = ws + off; off += (size_t)G * 45;
  float* a1     = ws + off; off += (size_t)G * 300;
  float* a2     = ws + off; off += (size_t)G * 300;
  float* xann   = ws + off; off += (size_t)G * 45;

  const int B = 256;
  const int gN = (N + B - 1) / B;
  const int vec_ok = ((E & 3) == 0) ? 1 : 0;
  const int nblk = (N + SCAN_ELEMS - 1) / SCAN_ELEMS;   // <=64 for N<=262144

  // ---- R20 direct counting-sort CSR build (replaces bucketed 5-kernel chain):
  // zero -> dhist (global atomics) -> 3-phase scan (+self-loop placement)
  // -> scatter (global atomics). Self loops never touch the edge passes.
  k_zero<<<(N + B - 1) / B, B, 0, stream>>>(rowcnt, N);
  k_dhist<<<HB_GRID, HB_BLK, 0, stream>>>(dstI, rowcnt, E, vec_ok);
  k_scan1<<<nblk, SCAN_BLK, 0, stream>>>(rowcnt, rowptr, blkSum, N);
  k_scan2<<<1, 64, 0, stream>>>(blkSum, nblk);
  k_scan3<<<(N + B - 1) / B, B, 0, stream>>>(rowcnt, rowptr, blkSum, rcur, csr, N, ET);
  k_scatter<<<HB_GRID, HB_BLK, 0, stream>>>(srcI, dstI, rcur, csr, E, vec_ok);

  // ---- weights ----
  const float* cW1  = (const float*)d_in[4];
  const float* cas1 = (const float*)d_in[5];
  const float* cad1 = (const float*)d_in[6];
  const float* cb1  = (const float*)d_in[7];
  const float* fW1  = (const float*)d_in[8];
  const float* fb1  = (const float*)d_in[9];
  const float* cW2  = (const float*)d_in[10];
  const float* cas2 = (const float*)d_in[11];
  const float* cad2 = (const float*)d_in[12];
  const float* cb2  = (const float*)d_in[13];
  const float* fW2  = (const float*)d_in[14];
  const float* fb2  = (const float*)d_in[15];
  const float* cW3  = (const float*)d_in[16];
  const float* cas3 = (const float*)d_in[17];
  const float* cad3 = (const float*)d_in[18];
  const float* cb3  = (const float*)d_in[19];
  const float* fW3  = (const float*)d_in[20];
  const float* fb3  = (const float*)d_in[21];
  const float* m1W  = (const float*)d_in[22];
  const float* m1b  = (const float*)d_in[23];
  const float* aW1  = (const float*)d_in[24];
  const float* ab1  = (const float*)d_in[25];
  const float* aW2  = (const float*)d_in[26];
  const float* ab2  = (const float*)d_in[27];
  const float* aW3  = (const float*)d_in[28];
  const float* ab3  = (const float*)d_in[29];
  const float* aW4  = (const float*)d_in[30];
  const float* ab4  = (const float*)d_in[31];
  const float* m2W  = (const float*)d_in[32];
  const float* m2b  = (const float*)d_in[33];

  // ---- 3 GAT layers, each carrying one annotation-MLP stage (R15 placement) --
  const int gGat = (N + 15) / 16;
  k_transform<<<gN, B, 0, stream>>>(x, FDIM, cW1, cas1, cad1, hpA, adA, N);
  k_gat<<<gGat + G, B, 0, stream>>>(rowptr, csr, hpA, adA, cb1, fW1, fb1,
                                    cW2, cas2, cad2, hpB, adB, nullptr,
                                    xA, aW1, ab1, a1, 300, 1, G,
                                    N, 1, 1);
  k_gat<<<gGat + G, B, 0, stream>>>(rowptr, csr, hpB, adB, cb2, fW2, fb2,
                                    cW3, cas3, cad3, hpA, adA, nullptr,
                                    a1, aW2, ab2, a2, 300, 1, G,
                                    N, 1, 1);
  k_gat<<<gGat + G, B, 0, stream>>>(rowptr, csr, hpA, adA, cb3, fW3, fb3,
                                    nullptr, nullptr, nullptr, nullptr, nullptr, fout,
                                    a2, aW3, ab3, a1, 300, 2, G,
                                    N, 0, 0);

  // ---- pooling + s4 rider ----
  k_pool<<<2 * G, B, 0, stream>>>(fout, batch, pooled, a1, aW4, ab4, xann, N, G);

  // ---- head ----
  k_final<<<G, 128, 0, stream>>>(pooled, xann, m1W, m1b, m2W, m2b, (float*)d_out);
}

// Round 5
// 319.064 us; speedup vs baseline: 2.1858x; 2.1858x over previous
//
#include <hip/hip_runtime.h>
#include <hip/hip_bf16.h>
#include <math.h>

#define FDIM 15
#define FPAD 16
#define NEG_SLOPE 0.2f
// dst-buckets of 256 nodes each: bucket = dst >> 8, local = dst & 255
#define BSH 8
#define BWID 256
// R5/R9 lesson (re-confirmed by R20's 196MB write-amplification failure):
// per-(block,bucket) chunk contiguity rules. Scattered 4B global writes
// cost ~64B/write of HBM traffic; always stage through bucket-packed
// segments. 256 blocks -> ~33 edges (132B) per chunk; 1024 thr/block.
#define HB_GRID 256
#define HB_BLK 1024

typedef _Float16 half_t;

__device__ __forceinline__ float leaky(float e) {
  return fmaxf(NEG_SLOPE * e, e);   // valid for slope<1
}

__global__ void k_zero(int* __restrict__ p, int n) {
  int i = blockIdx.x * blockDim.x + threadIdx.x;
  if (i < n) p[i] = 0;
}

// ---- bucket histogram over REAL edges only (R21: self-loops analytic) ----
// Dumps per-block histogram to bhistG so k_bpart skips its own first pass.
__global__ void k_bhist(const int* __restrict__ dstI, int* __restrict__ bcnt,
                        int* __restrict__ bhistG,
                        int E, int NB) {
  __shared__ int hist[512];
  int tid = threadIdx.x;
  for (int i = tid; i < NB; i += blockDim.x) hist[i] = 0;
  __syncthreads();
  int stride = gridDim.x * blockDim.x;
  for (int i = blockIdx.x * blockDim.x + tid; i < E; i += stride)
    atomicAdd(&hist[dstI[i] >> BSH], 1);
  __syncthreads();
  for (int i = tid; i < NB; i += blockDim.x) {
    int h = hist[i];
    bhistG[blockIdx.x * 512 + i] = h;
    if (h) atomicAdd(&bcnt[i], h);
  }
}

// ---- exclusive scan of bucket counts (single block, 512 thr) ----
// R21: bucket size = real edges + nodes_in_bucket (self-loops analytic).
__global__ void k_bscan(const int* __restrict__ bcnt, int* __restrict__ boff,
                        int* __restrict__ bcur, int* __restrict__ rowptr,
                        int NB, int N, int total) {
  __shared__ int s[512];
  int tid = threadIdx.x;
  int v = 0;
  if (tid < NB) {
    int rem = N - (tid << BSH);
    int nodes = rem < BWID ? rem : BWID;   // >=1 for tid<NB
    v = bcnt[tid] + nodes;
  }
  s[tid] = v;
  __syncthreads();
  for (int off = 1; off < 512; off <<= 1) {
    int add = (tid >= off) ? s[tid - off] : 0;
    __syncthreads();
    s[tid] += add;
    __syncthreads();
  }
  if (tid < NB) { int e = s[tid] - v; boff[tid] = e; bcur[tid] = e; }
  if (tid == NB - 1) boff[NB] = s[tid];
  if (tid == 0) rowptr[N] = total;
}

// ---- partition REAL edges into dst-buckets, packed (src<<8 | dst&255) ----
// Per-block hist comes from bhistG (R19). Self-loops never staged (R21).
__global__ void k_bpart(const int* __restrict__ srcI, const int* __restrict__ dstI,
                        int* __restrict__ bcur, int* __restrict__ bbuf,
                        const int* __restrict__ bhistG,
                        int E, int NB) {
  __shared__ int hist[512];
  __shared__ int base[512];
  int tid = threadIdx.x;
  for (int i = tid; i < NB; i += blockDim.x) {
    int h = bhistG[blockIdx.x * 512 + i];
    base[i] = h ? atomicAdd(&bcur[i], h) : 0;
    hist[i] = 0;
  }
  __syncthreads();
  int stride = gridDim.x * blockDim.x;
  for (int i = blockIdx.x * blockDim.x + tid; i < E; i += stride) {
    int s = srcI[i], d = dstI[i];
    int b = d >> BSH;
    int p = base[b] + atomicAdd(&hist[b], 1);
    bbuf[p] = (s << BSH) | (d & (BWID - 1));
  }
}

// ---- per-bucket: per-dst hist -> scan -> rowptr + csr scatter (512 thr) ----
// csr stores PRE-SCALED byte offsets (src*32) for k_gat's hp gathers.
// R21: row = [real edges (arrival order), self-loop]; self-loop written
// directly into csr (dense bucket window, no staging needed). Real-edge
// extent of the bucket segment = bcur[b] (bpart's final fill pointer).
__global__ void k_bbuild(const int* __restrict__ boff, const int* __restrict__ bend,
                         const int* __restrict__ bbuf,
                         int* __restrict__ rowptr, int* __restrict__ csr, int N) {
  __shared__ int hist[BWID];
  __shared__ int sc[BWID];
  int b = blockIdx.x;
  int tid = threadIdx.x;  // 512
  int base_dst = b << BSH;
  int nd = min(BWID, N - base_dst);
  int s0 = boff[b], s1 = bend[b];   // real edges staged in [s0, s1)
  if (tid < BWID) hist[tid] = 0;
  __syncthreads();
  for (int j = s0 + tid; j < s1; j += 512)
    atomicAdd(&hist[bbuf[j] & (BWID - 1)], 1);
  __syncthreads();
  int cnt = 0, add1 = 0;
  if (tid < BWID) {
    cnt = hist[tid];
    add1 = (tid < nd) ? cnt + 1 : 0;   // +1 slot for the self loop
    sc[tid] = add1;
  }
  __syncthreads();
  for (int off = 1; off < BWID; off <<= 1) {
    int add = 0;
    if (tid < BWID && tid >= off) add = sc[tid - off];
    __syncthreads();
    if (tid < BWID) sc[tid] += add;
    __syncthreads();
  }
  if (tid < nd) {
    int excl = sc[tid] - add1;
    rowptr[base_dst + tid] = s0 + excl;
    csr[s0 + excl + cnt] = (base_dst + tid) << 5;   // self loop at row end
  }
  __syncthreads();
  if (tid < BWID) hist[tid] = sc[tid] - add1;   // cursor base for real edges
  __syncthreads();
  for (int j = s0 + tid; j < s1; j += 512) {
    int e = bbuf[j];
    int dl = e & (BWID - 1);
    int p = s0 + atomicAdd(&hist[dl], 1);
    csr[p] = (e >> BSH) << 5;   // src * 32 bytes
  }
}

// ---- h = in @ W (fp16, as packed in slot 15) ; ad_ fp32 (layer 0 only) ----
__global__ void k_transform(const float* __restrict__ in, int ld_in,
                            const float* __restrict__ W,
                            const float* __restrict__ a_s,
                            const float* __restrict__ a_d,
                            half_t* __restrict__ hp,
                            float* __restrict__ ad_,
                            int n_nodes) {
  __shared__ float Ws[FDIM * FDIM];
  __shared__ float asv[FDIM], adv[FDIM];
  int tid = threadIdx.x;
  if (tid < FDIM * FDIM) Ws[tid] = W[tid];
  if (tid < FDIM) { asv[tid] = a_s[tid]; adv[tid] = a_d[tid]; }
  __syncthreads();
  int n = blockIdx.x * blockDim.x + tid;
  if (n >= n_nodes) return;
  float xin[FDIM];
#pragma unroll
  for (int j = 0; j < FDIM; ++j) xin[j] = in[n * ld_in + j];
  float sa = 0.f, da = 0.f;
  half_t hrow[FPAD];
#pragma unroll
  for (int o = 0; o < FDIM; ++o) {
    float acc = 0.f;
#pragma unroll
    for (int k = 0; k < FDIM; ++k) acc += xin[k] * Ws[k * FDIM + o];
    hrow[o] = (half_t)acc;
    sa += acc * asv[o];
    da += acc * adv[o];
  }
  hrow[FDIM] = (half_t)sa;
  ad_[n] = da;
  float4 w0, w1;
  __builtin_memcpy(&w0, &hrow[0], 16);
  __builtin_memcpy(&w1, &hrow[8], 16);
  float4* dst = (float4*)(hp + (size_t)n * FPAD);
  dst[0] = w0;
  dst[1] = w1;
}

// ---- annotation-MLP stage rider: 8-way explicit ILP (R16 lesson: rider
// block lifetime = displacement window; R11 lesson: only explicit scalar
// loads produce loads-in-flight on this compiler) ----
__device__ __forceinline__ void mlp_rider(int g, int tid, int nthreads,
                                          const float* __restrict__ mIn,
                                          const float* __restrict__ mW,
                                          const float* __restrict__ mB,
                                          float* __restrict__ mOut,
                                          int Nout, int mAct,
                                          float* mins) {
  for (int k = tid; k < 300; k += nthreads) mins[k] = mIn[(size_t)g * 300 + k];
  __syncthreads();
  int j1 = tid;
  int j2 = tid + nthreads;
  bool p1 = (j1 < Nout), p2 = (j2 < Nout);
  if (!p1) return;
  float a0 = 0.f, a1 = 0.f, a2 = 0.f, a3 = 0.f;
  float a4 = 0.f, a5 = 0.f, a6 = 0.f, a7 = 0.f;
  float b0 = 0.f, b1 = 0.f, b2 = 0.f, b3 = 0.f;
  float b4 = 0.f, b5 = 0.f, b6 = 0.f, b7 = 0.f;
  int k = 0;
  for (; k + 7 < 300; k += 8) {
    float i0 = mins[k],     i1 = mins[k + 1], i2 = mins[k + 2], i3 = mins[k + 3];
    float i4 = mins[k + 4], i5 = mins[k + 5], i6 = mins[k + 6], i7 = mins[k + 7];
    float w0 = mW[k * Nout + j1];
    float w1 = mW[(k + 1) * Nout + j1];
    float w2 = mW[(k + 2) * Nout + j1];
    float w3 = mW[(k + 3) * Nout + j1];
    float w4 = mW[(k + 4) * Nout + j1];
    float w5 = mW[(k + 5) * Nout + j1];
    float w6 = mW[(k + 6) * Nout + j1];
    float w7 = mW[(k + 7) * Nout + j1];
    a0 += i0 * w0; a1 += i1 * w1; a2 += i2 * w2; a3 += i3 * w3;
    a4 += i4 * w4; a5 += i5 * w5; a6 += i6 * w6; a7 += i7 * w7;
    if (p2) {
      float v0 = mW[k * Nout + j2];
      float v1 = mW[(k + 1) * Nout + j2];
      float v2 = mW[(k + 2) * Nout + j2];
      float v3 = mW[(k + 3) * Nout + j2];
      float v4 = mW[(k + 4) * Nout + j2];
      float v5 = mW[(k + 5) * Nout + j2];
      float v6 = mW[(k + 6) * Nout + j2];
      float v7 = mW[(k + 7) * Nout + j2];
      b0 += i0 * v0; b1 += i1 * v1; b2 += i2 * v2; b3 += i3 * v3;
      b4 += i4 * v4; b5 += i5 * v5; b6 += i6 * v6; b7 += i7 * v7;
    }
  }
  for (; k < 300; ++k) {
    float ik = mins[k];
    a0 += ik * mW[k * Nout + j1];
    if (p2) b0 += ik * mW[k * Nout + j2];
  }
  float r1 = mB[j1] + ((a0 + a1) + (a2 + a3)) + ((a4 + a5) + (a6 + a7));
  if (mAct == 1) r1 = fmaxf(r1, 0.f);
  else if (mAct == 2) r1 = 1.f / (1.f + expf(-r1));
  mOut[(size_t)g * Nout + j1] = r1;
  if (p2) {
    float r2 = mB[j2] + ((b0 + b1) + (b2 + b3)) + ((b4 + b5) + (b6 + b7));
    if (mAct == 1) r2 = fmaxf(r2, 0.f);
    else if (mAct == 2) r2 = 1.f / (1.f + expf(-r2));
    mOut[(size_t)g * Nout + j2] = r2;
  }
}

// ---- fused GAT aggregate + FFN (+ next-layer transform) + MLP rider ----
// R19: one-lane-per-edge. Lane f owns edge j+f whole: 1 coalesced csr
// load, 2x dwordx4 row gather (32B), sa local (no per-edge shfl), weight
// computed once per edge. Row epilogue: 15-shfl halving butterfly; lane f
// ends with feature brev4(f); slot 15 carries den. cb-bias and 1/den are
// folded into the FFN via cbW[o] = sum_k cb[k]*W[k][o].
__global__ void k_gat(const int* __restrict__ rowptr, const int* __restrict__ csrB,
                      const half_t* __restrict__ hp, const float* __restrict__ ad_,
                      const float* __restrict__ cb, const float* __restrict__ fW,
                      const float* __restrict__ fb,
                      const float* __restrict__ nW, const float* __restrict__ nas,
                      const float* __restrict__ nad,
                      half_t* __restrict__ hp2, float* __restrict__ ad2,
                      float* __restrict__ fout,
                      const float* __restrict__ mIn, const float* __restrict__ mW,
                      const float* __restrict__ mB, float* __restrict__ mOut,
                      int mNout, int mAct, int mlpG,
                      int n_nodes, int do_relu, int fuse) {
  __shared__ float Ws[FDIM * FDIM];
  __shared__ float W2s[FDIM * FDIM];
  __shared__ float cbv[FDIM], fbv[FDIM], as2v[FDIM], ad2v[FDIM];
  __shared__ float cbW[16];
  __shared__ float aggT[16][16];
  __shared__ float outT[16][16];
  __shared__ float mins[304];
  int tid = threadIdx.x;

  if ((int)blockIdx.x < mlpG) {
    mlp_rider(blockIdx.x, tid, blockDim.x, mIn, mW, mB, mOut, mNout, mAct, mins);
    return;
  }

  if (tid < FDIM * FDIM) Ws[tid] = fW[tid];
  if (tid < FDIM) { cbv[tid] = cb[tid]; fbv[tid] = fb[tid]; }
  if (fuse) {
    if (tid < FDIM * FDIM) W2s[tid] = nW[tid];
    if (tid < FDIM) { as2v[tid] = nas[tid]; ad2v[tid] = nad[tid]; }
  }
  __syncthreads();
  // fold cb into FFN: cbW[o] = sum_k cb[k] * W[k][o]
  if (tid < 16) {
    float s = 0.f;
    if (tid < FDIM) {
#pragma unroll
      for (int k = 0; k < FDIM; ++k) s += cbv[k] * Ws[k * FDIM + tid];
    }
    cbW[tid] = s;
  }
  int dl = tid >> 4;          // local dst 0..15
  int f  = tid & 15;          // lane-in-group = edge slot
  int d  = ((int)blockIdx.x - mlpG) * 16 + dl;
  if (d < n_nodes) {
    int rs = rowptr[d], re = rowptr[d + 1];   // re > rs always (self loop)
    int rlast = re - 1;
    float adv = ad_[d];
    const char* hb = (const char*)hp;
    float acc[16];
#pragma unroll
    for (int k = 0; k < 16; ++k) acc[k] = 0.f;

    // prologue: offsets+gathers for step 0; offsets for step 1
    int i0 = rs + f;
    int oA = csrB[i0 < re ? i0 : rlast];
    uint4 aLo = *(const uint4*)(hb + oA);
    uint4 aHi = *(const uint4*)(hb + oA + 16);
    int i1 = i0 + 16;
    int oB = csrB[i1 < re ? i1 : rlast];

    for (int j = rs; j < re; j += 16) {
      // gathers for next step
      uint4 bLo = *(const uint4*)(hb + oB);
      uint4 bHi = *(const uint4*)(hb + oB + 16);
      // offsets for step after next
      int i2 = j + 32 + f;
      int oC = csrB[i2 < re ? i2 : rlast];
      // compute current edge j+f
      half_t hv[16];
      __builtin_memcpy(hv, &aLo, 16);
      __builtin_memcpy(hv + 8, &aHi, 16);
      float sa = (float)hv[15];
      float w = (j + f < re) ? __expf(leaky(sa + adv)) : 0.f;
#pragma unroll
      for (int k = 0; k < FDIM; ++k) acc[k] += w * (float)hv[k];
      acc[15] += w;   // den rides in slot 15
      // rotate pipeline
      aLo = bLo; aHi = bHi; oB = oC;
    }

    // 16-lane halving butterfly: lane f ends with sum over lanes of
    // feature brev4(f) in acc[0] (slot 15 = den lands on lane 15).
    {
      bool hi = (f & 1);
#pragma unroll
      for (int i = 0; i < 8; ++i) {
        float send = hi ? acc[i] : acc[8 + i];
        float got = __shfl_xor(send, 1, 16);
        acc[i] = (hi ? acc[8 + i] : acc[i]) + got;
      }
      hi = (f & 2);
#pragma unroll
      for (int i = 0; i < 4; ++i) {
        float send = hi ? acc[i] : acc[4 + i];
        float got = __shfl_xor(send, 2, 16);
        acc[i] = (hi ? acc[4 + i] : acc[i]) + got;
      }
      hi = (f & 4);
#pragma unroll
      for (int i = 0; i < 2; ++i) {
        float send = hi ? acc[i] : acc[2 + i];
        float got = __shfl_xor(send, 4, 16);
        acc[i] = (hi ? acc[2 + i] : acc[i]) + got;
      }
      hi = (f & 8);
      {
        float send = hi ? acc[0] : acc[1];
        float got = __shfl_xor(send, 8, 16);
        acc[0] = (hi ? acc[1] : acc[0]) + got;
      }
    }
    int fb = ((f & 1) << 3) | ((f & 2) << 1) | ((f & 4) >> 1) | ((f & 8) >> 3);
    aggT[dl][fb] = acc[0];   // raw weighted sums; [15] = den
  }
  __syncthreads();
  int o = f;
  float ffn = 0.f;
  if (o < FDIM && d < n_nodes) {
    float inv = 1.f / (aggT[dl][15] + 1e-16f);
    float s = 0.f;
#pragma unroll
    for (int k = 0; k < FDIM; ++k) s += aggT[dl][k] * Ws[k * FDIM + o];
    ffn = fbv[o] + cbW[o] + s * inv;
    if (do_relu) ffn = fmaxf(ffn, 0.f);
  }
  if (!fuse) {
    if (d < n_nodes) fout[d * FPAD + o] = (o < FDIM) ? ffn : 0.f;
    return;
  }
  // ---- fused next-layer transform: h2 = out @ nW ; sa2/da2 reductions ----
  outT[dl][o] = ffn;   // o==15 lane wrote ffn=0; invalid-d rows unused
  __syncthreads();
  if (d < n_nodes) {
    float h2 = 0.f;
    if (o < FDIM) {
#pragma unroll
      for (int k = 0; k < FDIM; ++k) h2 += outT[dl][k] * W2s[k * FDIM + o];
    }
    float pa = (o < FDIM) ? h2 * as2v[o] : 0.f;
    float pd = (o < FDIM) ? h2 * ad2v[o] : 0.f;
#pragma unroll
    for (int k = 8; k; k >>= 1) {
      pa += __shfl_xor(pa, k, 16);
      pd += __shfl_xor(pd, k, 16);
    }
    hp2[(size_t)d * FPAD + o] = (half_t)((o < FDIM) ? h2 : pa);
    if (o == 0) ad2[d] = pd;
  }
}

// ---- pooling + s4 rider (xann = sigmoidActs @ aW4 + ab4) ----
__device__ __forceinline__ int lowerb(const int* __restrict__ a, int n, int key) {
  int lo = 0, hi = n;
  while (lo < hi) { int mid = (lo + hi) >> 1; if (a[mid] < key) lo = mid + 1; else hi = mid; }
  return lo;
}

__global__ void k_pool(const float* __restrict__ fout, const int* __restrict__ batch,
                       float* __restrict__ pooled,
                       const float* __restrict__ acts,
                       const float* __restrict__ aW4, const float* __restrict__ ab4,
                       float* __restrict__ xann,
                       int n_nodes, int Gn) {
  __shared__ float ss[256], sm[256];
  __shared__ float mins[304];
  int tid = threadIdx.x;
  if ((int)blockIdx.x < Gn) {
    mlp_rider(blockIdx.x, tid, blockDim.x, acts, aW4, ab4, xann, 45, 0, mins);
    return;
  }
  int g = blockIdx.x - Gn;
  int s = lowerb(batch, n_nodes, g);
  int e = lowerb(batch, n_nodes, g + 1);
  int f = tid & 15;
  float sum = 0.f, mx = -INFINITY;
  for (int n = s + (tid >> 4); n < e; n += 16) {
    float v = fout[n * FPAD + f];
    sum += v;
    mx = fmaxf(mx, v);
  }
  ss[tid] = sum; sm[tid] = mx;
  __syncthreads();
  for (int step = 128; step >= 16; step >>= 1) {
    if (tid < step) { ss[tid] += ss[tid + step]; sm[tid] = fmaxf(sm[tid], sm[tid + step]); }
    __syncthreads();
  }
  if (tid < FDIM) {
    float cnt = (float)(e - s);
    float sv = ss[tid];
    pooled[g * 45 + tid] = sv;
    pooled[g * 45 + 15 + tid] = sm[tid];
    pooled[g * 45 + 30 + tid] = sv / fmaxf(cnt, 1.f);
  }
}

// ---- head: z=[pooled,xann] -> relu(z@m1W+m1b) -> sigmoid(@m2W+m2b) ----
__global__ void k_final(const float* __restrict__ pooled, const float* __restrict__ xann,
                        const float* __restrict__ m1W, const float* __restrict__ m1b,
                        const float* __restrict__ m2W, const float* __restrict__ m2b,
                        float* __restrict__ out) {
  __shared__ float z[90];
  __shared__ float z2[90];
  __shared__ float ps[128];
  int g = blockIdx.x;
  int t = threadIdx.x;  // 128
  if (t < 45) z[t] = pooled[g * 45 + t];
  else if (t < 90) z[t] = xann[g * 45 + (t - 45)];
  __syncthreads();
  if (t < 90) {
    float a0 = 0.f, a1 = 0.f;
    for (int k = 0; k < 90; k += 2) {
      float w0 = m1W[k * 90 + t];
      float w1 = m1W[(k + 1) * 90 + t];
      a0 += z[k] * w0; a1 += z[k + 1] * w1;
    }
    z2[t] = fmaxf(m1b[t] + a0 + a1, 0.f);
  }
  __syncthreads();
  if (t < 90) ps[t] = z2[t] * m2W[t];
  else ps[t] = 0.f;
  __syncthreads();
  if (t < 64) {
    float v = ps[t] + ps[t + 64];
#pragma unroll
    for (int k2 = 32; k2; k2 >>= 1) v += __shfl_xor(v, k2, 64);
    if (t == 0) out[g] = 1.f / (1.f + expf(-(v + m2b[0])));
  }
}

extern "C" void kernel_launch(void* const* d_in, const int* in_sizes, int n_in,
                              void* d_out, int out_size, void* d_ws, size_t ws_size,
                              hipStream_t stream) {
  const float* x   = (const float*)d_in[0];
  const int* ei    = (const int*)d_in[1];
  const int* batch = (const int*)d_in[2];
  const float* xA  = (const float*)d_in[3];

  const int N = in_sizes[0] / FDIM;
  const int E = in_sizes[1] / 2;
  const int G = in_sizes[3] / 300;
  const int ET = E + N;
  const int NB = (N + BWID - 1) >> BSH;   // dst buckets (<=512 for N<=131072)

  const int* srcI = ei;
  const int* dstI = ei + E;

  // ---- workspace layout (4-byte words) ----
  float* ws = (float*)d_ws;
  size_t layerW = (size_t)34 * N;  // hpA(8N)+hpB(8N)+adA(N)+adB(N)+fout(16N)
  size_t uSize = layerW > (size_t)ET ? layerW : (size_t)ET;
  size_t off = 0;
  int*    bbuf = (int*)(ws + off);
  half_t* hpA  = (half_t*)(ws + off);
  half_t* hpB  = (half_t*)(ws + off + (size_t)8 * N);
  float*  adA  = ws + off + (size_t)16 * N;
  float*  adB  = ws + off + (size_t)17 * N;
  float*  fout = ws + off + (size_t)18 * N;
  off += uSize;
  int*   rowptr = (int*)(ws + off); off += N + 1;
  int*   csr    = (int*)(ws + off); off += (size_t)ET;
  int*   bcnt   = (int*)(ws + off); off += 516;
  int*   boff   = (int*)(ws + off); off += 516;
  int*   bcur   = (int*)(ws + off); off += 516;
  int*   bhistG = (int*)(ws + off); off += (size_t)512 * HB_GRID;
  float* pooled = ws + off; off += (size_t)G * 45;
  float* a1     = ws + off; off += (size_t)G * 300;
  float* a2     = ws + off; off += (size_t)G * 300;
  float* xann   = ws + off; off += (size_t)G * 45;

  const int B = 256;
  const int gN = (N + B - 1) / B;

  // ---- bucketed CSR build (R15 two-pass; R19 hist reuse; R21 analytic
  // self-loops: real edges staged, self-loop written at each row's end) ----
  k_zero<<<(NB + B - 1) / B, B, 0, stream>>>(bcnt, NB);
  k_bhist<<<HB_GRID, HB_BLK, 0, stream>>>(dstI, bcnt, bhistG, E, NB);
  k_bscan<<<1, 512, 0, stream>>>(bcnt, boff, bcur, rowptr, NB, N, ET);
  k_bpart<<<HB_GRID, HB_BLK, 0, stream>>>(srcI, dstI, bcur, bbuf, bhistG, E, NB);
  k_bbuild<<<NB, 512, 0, stream>>>(boff, bcur, bbuf, rowptr, csr, N);

  // ---- weights ----
  const float* cW1  = (const float*)d_in[4];
  const float* cas1 = (const float*)d_in[5];
  const float* cad1 = (const float*)d_in[6];
  const float* cb1  = (const float*)d_in[7];
  const float* fW1  = (const float*)d_in[8];
  const float* fb1  = (const float*)d_in[9];
  const float* cW2  = (const float*)d_in[10];
  const float* cas2 = (const float*)d_in[11];
  const float* cad2 = (const float*)d_in[12];
  const float* cb2  = (const float*)d_in[13];
  const float* fW2  = (const float*)d_in[14];
  const float* fb2  = (const float*)d_in[15];
  const float* cW3  = (const float*)d_in[16];
  const float* cas3 = (const float*)d_in[17];
  const float* cad3 = (const float*)d_in[18];
  const float* cb3  = (const float*)d_in[19];
  const float* fW3  = (const float*)d_in[20];
  const float* fb3  = (const float*)d_in[21];
  const float* m1W  = (const float*)d_in[22];
  const float* m1b  = (const float*)d_in[23];
  const float* aW1  = (const float*)d_in[24];
  const float* ab1  = (const float*)d_in[25];
  const float* aW2  = (const float*)d_in[26];
  const float* ab2  = (const float*)d_in[27];
  const float* aW3  = (const float*)d_in[28];
  const float* ab3  = (const float*)d_in[29];
  const float* aW4  = (const float*)d_in[30];
  const float* ab4  = (const float*)d_in[31];
  const float* m2W  = (const float*)d_in[32];
  const float* m2b  = (const float*)d_in[33];

  // ---- 3 GAT layers, each carrying one annotation-MLP stage (R15 placement) --
  const int gGat = (N + 15) / 16;
  k_transform<<<gN, B, 0, stream>>>(x, FDIM, cW1, cas1, cad1, hpA, adA, N);
  k_gat<<<gGat + G, B, 0, stream>>>(rowptr, csr, hpA, adA, cb1, fW1, fb1,
                                    cW2, cas2, cad2, hpB, adB, nullptr,
                                    xA, aW1, ab1, a1, 300, 1, G,
                                    N, 1, 1);
  k_gat<<<gGat + G, B, 0, stream>>>(rowptr, csr, hpB, adB, cb2, fW2, fb2,
                                    cW3, cas3, cad3, hpA, adA, nullptr,
                                    a1, aW2, ab2, a2, 300, 1, G,
                                    N, 1, 1);
  k_gat<<<gGat + G, B, 0, stream>>>(rowptr, csr, hpA, adA, cb3, fW3, fb3,
                                    nullptr, nullptr, nullptr, nullptr, nullptr, fout,
                                    a2, aW3, ab3, a1, 300, 2, G,
                                    N, 0, 0);

  // ---- pooling + s4 rider ----
  k_pool<<<2 * G, B, 0, stream>>>(fout, batch, pooled, a1, aW4, ab4, xann, N, G);

  // ---- head ----
  k_final<<<G, 128, 0, stream>>>(pooled, xann, m1W, m1b, m2W, m2b, (float*)d_out);
}